// Round 18
// baseline (241.287 us; speedup 1.0000x reference)
//
#include <hip/hip_runtime.h>
#include <hip/hip_bf16.h>

typedef __hip_bfloat16 bf16;
typedef short bf16x8 __attribute__((ext_vector_type(8)));
typedef float f32x4 __attribute__((ext_vector_type(4)));
typedef float f32x2 __attribute__((ext_vector_type(2)));
typedef int i32x4 __attribute__((ext_vector_type(4)));
typedef unsigned u32x4 __attribute__((ext_vector_type(4)));

#define N_NODES 100000
#define N_EDGES 3200000
#define N_GRAPHS 512
#define NBKT    ((N_NODES + 255) / 256)               // 391 buckets of 256 nodes
#define CAP     11776                                 // slots per bucket window (16-aligned)
#define EPB     16384                                 // edges per k_bucket block
#define NBLK_A  ((N_EDGES + EPB - 1) / EPB)           // 196
#define FP4_SCALE 16.0f
#define FP4_INV   (1.0f / 16.0f)

// ---------- fp4 e2m1 decode ----------

__device__ inline void accf4(f32x2* ae, f32x2* ao, unsigned d) {
#if __has_builtin(__builtin_amdgcn_cvt_pk_f32_fp8) && __has_builtin(__builtin_amdgcn_perm)
    unsigned lo8 = __builtin_amdgcn_perm(0x4C484440u, 0x3C383000u, d & 0x07070707u)
                 | ((d & 0x08080808u) << 4);
    unsigned hi8 = __builtin_amdgcn_perm(0x4C484440u, 0x3C383000u, (d >> 4) & 0x07070707u)
                 | (d & 0x80808080u);
    ae[0] += __builtin_amdgcn_cvt_pk_f32_fp8((int)lo8, false);
    ae[1] += __builtin_amdgcn_cvt_pk_f32_fp8((int)lo8, true);
    ao[0] += __builtin_amdgcn_cvt_pk_f32_fp8((int)hi8, false);
    ao[1] += __builtin_amdgcn_cvt_pk_f32_fp8((int)hi8, true);
#else
    #pragma unroll
    for (int i = 0; i < 4; ++i) {
        unsigned by = (d >> (8 * i)) & 0xFFu;
        unsigned ln = by & 7u, hn = (by >> 4) & 7u;
        float lv = (ln < 2) ? (float)ln * 0.5f : 0.5f * (float)(1 << ((ln >> 1) - 1)) * (2 + (ln & 1));
        float hv = (hn < 2) ? (float)hn * 0.5f : 0.5f * (float)(1 << ((hn >> 1) - 1)) * (2 + (hn & 1));
        if (by & 8u) lv = -lv;
        if (by & 0x80u) hv = -hv;
        ae[i >> 1][i & 1] += lv;
        ao[i >> 1][i & 1] += hv;
    }
#endif
}

__device__ inline unsigned fp4n(float v) {
    unsigned s = (__float_as_uint(v) >> 28) & 8u;
    float x = fabsf(v);
    unsigned n = (unsigned)(x >= 0.25f) + (x >= 0.75f) + (x >= 1.25f) + (x >= 1.75f)
               + (x >= 2.5f) + (x >= 3.5f) + (x >= 5.0f);
    return s | n;
}

__device__ inline unsigned short f2bf(float x) {
    unsigned u = __float_as_uint(x);
    return (unsigned short)((u + 0x7FFF + ((u >> 16) & 1)) >> 16);
}

// ---------- setup: Wc/bc, Wfrag, gcur, dcnt, dummy rows ----------

__global__ void k_setup(const float* __restrict__ W_emb, const float* __restrict__ b_emb,
                        const float* __restrict__ W1, const float* __restrict__ W2,
                        const float* __restrict__ W3, const float* __restrict__ W4,
                        float* __restrict__ Wc, float* __restrict__ bc,
                        unsigned short* __restrict__ Wfrag, int* __restrict__ gcur,
                        int* __restrict__ dcnt,
                        unsigned* __restrict__ ta, unsigned* __restrict__ tb) {
    int blk = blockIdx.x, t = threadIdx.x;
    if (blk == 0) {
        for (int i = t; i < 32 * 64; i += 256) {
            int a = i / 64, b = i % 64;
            float acc = 0.f;
            for (int k = 0; k < 64; ++k) acc += W_emb[a * 64 + k] * W1[k * 64 + b];
            Wc[i] = acc;
        }
        if (t < 64) {
            float acc = 0.f;
            for (int k = 0; k < 64; ++k) acc += b_emb[k] * W1[k * 64 + t];
            bc[t] = acc;
        }
    } else if (blk <= 3) {
        const float* W = (blk == 1) ? W2 : (blk == 2) ? W3 : W4;
        unsigned short* dst = Wfrag + (size_t)(blk - 1) * 4096;
        for (int i = 0; i < 16; ++i) {
            int flat = t * 16 + i;
            int j = flat & 7, lane = (flat >> 3) & 63, mt = (flat >> 9) & 3, kt = flat >> 11;
            int m = mt * 16 + (lane & 15);
            int k = kt * 32 + ((lane >> 4) << 3) + j;
            dst[flat] = f2bf(W[k * 64 + m]);
        }
    } else {
        for (int b = t; b < NBKT; b += 256) gcur[b] = b * CAP;
        dcnt[t] = 0;
        if (t < 8) {
            size_t o = (size_t)N_NODES * 8 + t;
            ta[o] = 0; tb[o] = 0;
        }
    }
}

// ---------- Pass A: bin edges by dst>>8, per-wave LDS histograms ----------

__global__ void __launch_bounds__(512) k_bucket(const int* __restrict__ ei,
                                                int* __restrict__ gcur,
                                                int* __restrict__ ebuf) {
    __shared__ int cnt[8][NBKT];
    __shared__ int base[8][NBKT];
    int t = threadIdx.x, w = t >> 6;
    for (int i = t; i < 8 * NBKT; i += 512) ((int*)cnt)[i] = 0;
    __syncthreads();
    int e0 = blockIdx.x * EPB + t;
    int sv[32], dv[32];
    #pragma unroll
    for (int j = 0; j < 32; ++j) {
        int e = e0 + j * 512;
        if (e < N_EDGES) {
            sv[j] = ei[e];
            dv[j] = ei[N_EDGES + e];
            atomicAdd(&cnt[w][dv[j] >> 8], 1);
        } else dv[j] = -1;
    }
    __syncthreads();
    for (int b = t; b < NBKT; b += 512) {
        int tot = 0, c[8];
        #pragma unroll
        for (int ww = 0; ww < 8; ++ww) { c[ww] = cnt[ww][b]; tot += c[ww]; }
        int g = tot ? atomicAdd(&gcur[b], tot) : 0;
        #pragma unroll
        for (int ww = 0; ww < 8; ++ww) { base[ww][b] = g; g += c[ww]; cnt[ww][b] = 0; }
    }
    __syncthreads();
    #pragma unroll
    for (int j = 0; j < 32; ++j) {
        if (dv[j] >= 0) {
            int b = dv[j] >> 8;
            int r = atomicAdd(&cnt[w][b], 1);
            ebuf[base[w][b] + r] = (sv[j] << 8) | (dv[j] & 255);
        }
    }
}

// ---------- Pass B: per-bucket histogram -> rc/dis, 16-aligned col, pad-gap dummies;
//            also global degree histogram for the sort ----------

__global__ void __launch_bounds__(256) k_fill2(const int* __restrict__ ebuf,
                                               const int* __restrict__ gcur,
                                               int2* __restrict__ rc,
                                               float* __restrict__ dis,
                                               int* __restrict__ col,
                                               int* __restrict__ dcnt) {
    __shared__ int cnt[256];
    __shared__ int sc[256];
    __shared__ int exs[256];
    __shared__ int cur[256];
    __shared__ int dh[256];
    int b = blockIdx.x, t = threadIdx.x;
    int n0 = b * 256;
    int nrec = gcur[b] - b * CAP;
    const int* eb = ebuf + (size_t)b * CAP;
    int* cw = col + (size_t)b * CAP;
    cnt[t] = 0; cur[t] = 0; dh[t] = 0;
    __syncthreads();
    for (int i = t; i < nrec; i += 256)
        atomicAdd(&cnt[eb[i] & 255], 1);
    __syncthreads();
    int c0 = cnt[t];
    int a16 = (c0 + 15) & ~15;
    sc[t] = a16; __syncthreads();
    for (int off = 1; off < 256; off <<= 1) {
        int u = (t >= off) ? sc[t - off] : 0;
        __syncthreads();
        sc[t] += u;
        __syncthreads();
    }
    int myex = sc[t] - a16;
    exs[t] = myex;
    int n = n0 + t;
    if (n < N_NODES) {
        rc[n] = make_int2(b * CAP + myex, c0);
        dis[n] = rsqrtf((float)(c0 + 1));
        atomicAdd(&dh[min(c0, 255)], 1);            // degree histogram (local)
    }
    for (int i = myex + c0; i < myex + a16; ++i) cw[i] = N_NODES;
    __syncthreads();
    if (dh[t]) atomicAdd(&dcnt[t], dh[t]);          // flush to global
    for (int i = t; i < nrec; i += 256) {
        int rec = eb[i];
        int dl = rec & 255;
        cw[exs[dl] + atomicAdd(&cur[dl], 1)] = rec >> 8;
    }
}

// ---------- degree-sort: scan histogram, then bucketed scatter of node ids ----------

__global__ void k_dscan(const int* __restrict__ dcnt, int* __restrict__ dbase) {
    __shared__ int lds[256];
    int t = threadIdx.x;
    int v = dcnt[t];
    lds[t] = v; __syncthreads();
    for (int off = 1; off < 256; off <<= 1) {
        int u = (t >= off) ? lds[t - off] : 0;
        __syncthreads();
        lds[t] += u;
        __syncthreads();
    }
    dbase[t] = lds[t] - v;                           // exclusive scan
}

__global__ void __launch_bounds__(256) k_dsort(const int2* __restrict__ rc,
                                               int* __restrict__ dbase,
                                               int* __restrict__ perm) {
    __shared__ int cnt[256];
    __shared__ int base[256];
    int b = blockIdx.x, t = threadIdx.x;
    int n = b * 256 + t;
    int bin = -1;
    if (n < N_NODES) bin = min(rc[n].y, 255);
    cnt[t] = 0;
    __syncthreads();
    if (bin >= 0) atomicAdd(&cnt[bin], 1);
    __syncthreads();
    if (cnt[t]) base[t] = atomicAdd(&dbase[t], cnt[t]);
    cnt[t] = 0;
    __syncthreads();
    if (bin >= 0) {
        int r = atomicAdd(&cnt[bin], 1);
        perm[base[bin] + r] = n;
    }
}

// ---------- layer-1 matmul -> fp4 table (nibble-packed, 32B rows) ----------

__global__ void __launch_bounds__(256) k_mm1(const float* __restrict__ inp,
                                             const float* __restrict__ W,
                                             const float* __restrict__ bias,
                                             const float* __restrict__ dis,
                                             unsigned char* __restrict__ T) {
    __shared__ float Wl[32][64];
    __shared__ float hs[16][32];
    int t = threadIdx.x;
    for (int i = t; i < 32 * 64; i += 256) Wl[i / 64][i % 64] = W[i];
    int row0 = blockIdx.x * 16;
    for (int i = t; i < 16 * 32; i += 256) {
        int r = row0 + i / 32, k = i % 32;
        hs[i / 32][k] = inp[(size_t)r * 32 + k];
    }
    __syncthreads();
    int c = t & 63, rg = t >> 6;
    float a0 = 0, a1 = 0, a2 = 0, a3 = 0;
    #pragma unroll 4
    for (int k = 0; k < 32; ++k) {
        float wv = Wl[k][c];
        a0 += hs[rg * 4 + 0][k] * wv;
        a1 += hs[rg * 4 + 1][k] * wv;
        a2 += hs[rg * 4 + 2][k] * wv;
        a3 += hs[rg * 4 + 3][k] * wv;
    }
    float bv = bias[c];
    int r = row0 + rg * 4;
    unsigned n0 = fp4n(FP4_SCALE * dis[r + 0] * (a0 + bv));
    unsigned n1 = fp4n(FP4_SCALE * dis[r + 1] * (a1 + bv));
    unsigned n2 = fp4n(FP4_SCALE * dis[r + 2] * (a2 + bv));
    unsigned n3 = fp4n(FP4_SCALE * dis[r + 3] * (a3 + bv));
    unsigned p0 = __shfl_xor(n0, 1), p1 = __shfl_xor(n1, 1);
    unsigned p2 = __shfl_xor(n2, 1), p3 = __shfl_xor(n3, 1);
    if ((c & 1) == 0) {
        size_t boff = (size_t)(c >> 1);
        T[(size_t)(r + 0) * 32 + boff] = (unsigned char)(n0 | (p0 << 4));
        T[(size_t)(r + 1) * 32 + boff] = (unsigned char)(n1 | (p1 << 4));
        T[(size_t)(r + 2) * 32 + boff] = (unsigned char)(n2 | (p2 << 4));
        T[(size_t)(r + 3) * 32 + boff] = (unsigned char)(n3 | (p3 << 4));
    }
}

// ---------- FUSED AGG + COMBINE (fp4): degree-sorted rows via perm ----------

template<bool LAST>
__global__ void __launch_bounds__(256, 8) k_aggc(const unsigned* __restrict__ tph,
                                                 const int2* __restrict__ rc,
                                                 const int* __restrict__ col,
                                                 const int* __restrict__ perm,
                                                 const float* __restrict__ dis,
                                                 const float* __restrict__ bias,
                                                 const unsigned short* __restrict__ Wfrag,
                                                 unsigned char* __restrict__ Tn,
                                                 unsigned short* __restrict__ hout) {
    __shared__ unsigned short h_lds[32][72];
    int t = threadIdx.x;
    int rowbase = blockIdx.x * 32;
    int li = t >> 3;                                   // local row 0..31
    int row = perm[rowbase + li];
    int sl = t & 7;
    f32x2 ae[2] = {{0.f, 0.f}, {0.f, 0.f}};
    f32x2 ao[2] = {{0.f, 0.f}, {0.f, 0.f}};
    accf4(ae, ao, tph[(size_t)row * 8 + sl]);          // self-loop term
    int2 r = rc[row];
    int nit = (r.y + 15) >> 4;                         // 16-edge iterations
    const int* cp = col + r.x;
    if (nit > 0) {
        i32x4 c0 = *(const i32x4*)(cp + 0);
        i32x4 c1 = *(const i32x4*)(cp + 4);
        i32x4 c2 = *(const i32x4*)(cp + 8);
        i32x4 c3 = *(const i32x4*)(cp + 12);
        for (int it = 1; ; ++it) {
            unsigned v0  = tph[(size_t)c0.x * 8 + sl];
            unsigned v1  = tph[(size_t)c0.y * 8 + sl];
            unsigned v2  = tph[(size_t)c0.z * 8 + sl];
            unsigned v3  = tph[(size_t)c0.w * 8 + sl];
            unsigned v4  = tph[(size_t)c1.x * 8 + sl];
            unsigned v5  = tph[(size_t)c1.y * 8 + sl];
            unsigned v6  = tph[(size_t)c1.z * 8 + sl];
            unsigned v7  = tph[(size_t)c1.w * 8 + sl];
            unsigned v8  = tph[(size_t)c2.x * 8 + sl];
            unsigned v9  = tph[(size_t)c2.y * 8 + sl];
            unsigned v10 = tph[(size_t)c2.z * 8 + sl];
            unsigned v11 = tph[(size_t)c2.w * 8 + sl];
            unsigned v12 = tph[(size_t)c3.x * 8 + sl];
            unsigned v13 = tph[(size_t)c3.y * 8 + sl];
            unsigned v14 = tph[(size_t)c3.z * 8 + sl];
            unsigned v15 = tph[(size_t)c3.w * 8 + sl];
            bool more = it < nit;
            if (more) {                                // prefetch next 16 cols
                const int* np = cp + it * 16;
                c0 = *(const i32x4*)(np + 0);
                c1 = *(const i32x4*)(np + 4);
                c2 = *(const i32x4*)(np + 8);
                c3 = *(const i32x4*)(np + 12);
            }
            accf4(ae, ao, v0);  accf4(ae, ao, v1);  accf4(ae, ao, v2);  accf4(ae, ao, v3);
            accf4(ae, ao, v4);  accf4(ae, ao, v5);  accf4(ae, ao, v6);  accf4(ae, ao, v7);
            accf4(ae, ao, v8);  accf4(ae, ao, v9);  accf4(ae, ao, v10); accf4(ae, ao, v11);
            accf4(ae, ao, v12); accf4(ae, ao, v13); accf4(ae, ao, v14); accf4(ae, ao, v15);
            if (!more) break;
        }
    }
    // h = relu(dis/S * agg + bias)
    float ds = dis[row] * FP4_INV;
    int f0 = sl * 8;
    float h0 = fmaxf(ds * ae[0].x + bias[f0 + 0], 0.f);
    float h1 = fmaxf(ds * ao[0].x + bias[f0 + 1], 0.f);
    float h2 = fmaxf(ds * ae[0].y + bias[f0 + 2], 0.f);
    float h3 = fmaxf(ds * ao[0].y + bias[f0 + 3], 0.f);
    float h4 = fmaxf(ds * ae[1].x + bias[f0 + 4], 0.f);
    float h5 = fmaxf(ds * ao[1].x + bias[f0 + 5], 0.f);
    float h6 = fmaxf(ds * ae[1].y + bias[f0 + 6], 0.f);
    float h7 = fmaxf(ds * ao[1].y + bias[f0 + 7], 0.f);
    u32x4 o;
    o.x = (unsigned)f2bf(h0) | ((unsigned)f2bf(h1) << 16);
    o.y = (unsigned)f2bf(h2) | ((unsigned)f2bf(h3) << 16);
    o.z = (unsigned)f2bf(h4) | ((unsigned)f2bf(h5) << 16);
    o.w = (unsigned)f2bf(h6) | ((unsigned)f2bf(h7) << 16);
    if (LAST) {
        *(u32x4*)(hout + (size_t)row * 64 + f0) = o;
        return;
    }
    *(u32x4*)&h_lds[li][f0] = o;
    __syncthreads();
    // MFMA: wave w handles row-group (w&1), mt-tiles {2*(w>>1), 2*(w>>1)+1}
    int w = t >> 6, l = t & 63;
    int rg = w & 1, mt0 = (w >> 1) << 1;
    f32x4 acc[2] = {{0, 0, 0, 0}, {0, 0, 0, 0}};
    const bf16x8* wf = (const bf16x8*)Wfrag;
    #pragma unroll
    for (int kt = 0; kt < 2; ++kt) {
        bf16x8 bfr = *(const bf16x8*)&h_lds[rg * 16 + (l & 15)][kt * 32 + ((l >> 4) << 3)];
        #pragma unroll
        for (int mi = 0; mi < 2; ++mi) {
            bf16x8 afr = wf[(kt * 4 + mt0 + mi) * 64 + l];
            acc[mi] = __builtin_amdgcn_mfma_f32_16x16x32_bf16(afr, bfr, acc[mi], 0, 0, 0);
        }
    }
    int hrow = perm[rowbase + rg * 16 + (l & 15)];
    float sc2 = FP4_SCALE * dis[hrow];
    #pragma unroll
    for (int mi = 0; mi < 2; ++mi) {
        int colbase = (mt0 + mi) * 16 + ((l >> 4) << 2);
        unsigned short v = (unsigned short)(fp4n(sc2 * acc[mi][0])
                           | (fp4n(sc2 * acc[mi][1]) << 4)
                           | (fp4n(sc2 * acc[mi][2]) << 8)
                           | (fp4n(sc2 * acc[mi][3]) << 12));
        *(unsigned short*)(Tn + (size_t)hrow * 32 + (colbase >> 1)) = v;
    }
}

// ---------- pool (h pre-activated) + MLP head + log_softmax ----------

__global__ void __launch_bounds__(256) k_poolhead(const unsigned short* __restrict__ h,
                                                  const int* __restrict__ batch,
                                                  const float* __restrict__ Wr1, const float* __restrict__ br1,
                                                  const float* __restrict__ Wr2, const float* __restrict__ br2,
                                                  const float* __restrict__ Wr3, const float* __restrict__ br3,
                                                  float* __restrict__ out) {
    __shared__ float part[4][64];
    __shared__ float p[64], r1[32], r2[16], lg[10];
    __shared__ int seg[2];
    int g = blockIdx.x, t = threadIdx.x;
    if (t < 2) {
        int key = g + t;
        int lo = 0, hi = N_NODES;
        while (lo < hi) { int m = (lo + hi) >> 1; if (batch[m] < key) lo = m + 1; else hi = m; }
        seg[t] = lo;
    }
    __syncthreads();
    int start = seg[0], end = seg[1];
    int w = t >> 6, grp = (t >> 4) & 3, sl = t & 15;
    float a[4] = {0.f, 0.f, 0.f, 0.f};
    for (int r = start + w * 4 + grp; r < end; r += 16) {
        ushort4 v = *(const ushort4*)(h + (size_t)r * 64 + sl * 4);
        a[0] += __uint_as_float((unsigned)v.x << 16);
        a[1] += __uint_as_float((unsigned)v.y << 16);
        a[2] += __uint_as_float((unsigned)v.z << 16);
        a[3] += __uint_as_float((unsigned)v.w << 16);
    }
    #pragma unroll
    for (int j = 0; j < 4; ++j) {
        a[j] += __shfl_xor(a[j], 16);
        a[j] += __shfl_xor(a[j], 32);
    }
    if (sl == (t & 63)) {
        #pragma unroll
        for (int j = 0; j < 4; ++j) part[w][sl * 4 + j] = a[j];
    }
    __syncthreads();
    if (t < 64) {
        float s = part[0][t] + part[1][t] + part[2][t] + part[3][t];
        float c = fmaxf((float)(end - start), 1.f);
        p[t] = s / c;
    }
    __syncthreads();
    if (t < 32) {
        float acc = br1[t];
        for (int k = 0; k < 64; ++k) acc += p[k] * Wr1[k * 32 + t];
        r1[t] = fmaxf(acc, 0.f);
    }
    __syncthreads();
    if (t < 16) {
        float acc = br2[t];
        for (int k = 0; k < 32; ++k) acc += r1[k] * Wr2[k * 16 + t];
        r2[t] = fmaxf(acc, 0.f);
    }
    __syncthreads();
    if (t < 10) {
        float acc = br3[t];
        for (int k = 0; k < 16; ++k) acc += r2[k] * Wr3[k * 10 + t];
        lg[t] = acc;
    }
    __syncthreads();
    if (t < 10) {
        float m = -1e30f;
        for (int j = 0; j < 10; ++j) m = fmaxf(m, lg[j]);
        float s = 0.f;
        for (int j = 0; j < 10; ++j) s += expf(lg[j] - m);
        out[g * 10 + t] = lg[t] - m - logf(s);
    }
}

extern "C" void kernel_launch(void* const* d_in, const int* in_sizes, int n_in,
                              void* d_out, int out_size, void* d_ws, size_t ws_size,
                              hipStream_t stream) {
    const float* x     = (const float*)d_in[0];
    const int*   ei    = (const int*)d_in[1];
    const int*   batch = (const int*)d_in[2];
    const float* W_emb = (const float*)d_in[4];
    const float* b_emb = (const float*)d_in[5];
    const float* W1    = (const float*)d_in[6];
    const float* b1    = (const float*)d_in[7];
    const float* W2    = (const float*)d_in[8];
    const float* b2    = (const float*)d_in[9];
    const float* W3    = (const float*)d_in[10];
    const float* b3    = (const float*)d_in[11];
    const float* W4    = (const float*)d_in[12];
    const float* b4    = (const float*)d_in[13];
    const float* Wr1   = (const float*)d_in[14];
    const float* br1   = (const float*)d_in[15];
    const float* Wr2   = (const float*)d_in[16];
    const float* br2   = (const float*)d_in[17];
    const float* Wr3   = (const float*)d_in[18];
    const float* br3   = (const float*)d_in[19];
    float* out = (float*)d_out;

    char* ws = (char*)d_ws;
    size_t off = 0;
    auto alloc = [&](size_t b) { char* p = ws + off; off += (b + 511) & ~(size_t)511; return p; };
    size_t TBYTES = (size_t)(N_NODES + 1) * 32;
    int*   col    = (int*)  alloc((size_t)NBKT * CAP * 4);     // 18.4 MB
    int*   ebuf   = (int*)  alloc((size_t)NBKT * CAP * 4);     // later reused as hout
    unsigned char* Ta = (unsigned char*)alloc(TBYTES);         // fp4 tables (+dummy row)
    unsigned char* Tb = (unsigned char*)alloc(TBYTES);
    int2*  rc     = (int2*) alloc((size_t)N_NODES * 8);
    float* dis    = (float*)alloc((size_t)N_NODES * 4);
    int*   perm   = (int*)  alloc((size_t)(NBKT * 256) * 4);
    int*   gcur   = (int*)  alloc((size_t)NBKT * 4);
    int*   dcnt   = (int*)  alloc(256 * 4);
    int*   dbase  = (int*)  alloc(256 * 4);
    float* Wc     = (float*)alloc(32 * 64 * 4);
    float* bc     = (float*)alloc(64 * 4);
    unsigned short* Wfrag = (unsigned short*)alloc(3 * 4096 * 2);

    unsigned short* hout = (unsigned short*)ebuf;    // alias: h lives where ebuf was

    k_setup<<<5, 256, 0, stream>>>(W_emb, b_emb, W1, W2, W3, W4, Wc, bc, Wfrag, gcur,
                                   dcnt, (unsigned*)Ta, (unsigned*)Tb);
    k_bucket<<<NBLK_A, 512, 0, stream>>>(ei, gcur, ebuf);
    k_fill2<<<NBKT, 256, 0, stream>>>(ebuf, gcur, rc, dis, col, dcnt);
    k_dscan<<<1, 256, 0, stream>>>(dcnt, dbase);
    k_dsort<<<NBKT, 256, 0, stream>>>(rc, dbase, perm);

    int nbm = N_NODES / 16;        // 6250
    int nba = (N_NODES + 31) / 32; // 3125

    k_mm1<<<nbm, 256, 0, stream>>>(x, Wc, bc, dis, Ta);

    // layers 1-3: fused agg+combine, ping-pong fp4 tables (degree-sorted rows)
    k_aggc<false><<<nba, 256, 0, stream>>>((const unsigned*)Ta, rc, col, perm, dis, b1,
                                           Wfrag + 0 * 4096, Tb, nullptr);
    k_aggc<false><<<nba, 256, 0, stream>>>((const unsigned*)Tb, rc, col, perm, dis, b2,
                                           Wfrag + 1 * 4096, Ta, nullptr);
    k_aggc<false><<<nba, 256, 0, stream>>>((const unsigned*)Ta, rc, col, perm, dis, b3,
                                           Wfrag + 2 * 4096, Tb, nullptr);
    // layer 4: fused agg + bias/relu -> h
    k_aggc<true><<<nba, 256, 0, stream>>>((const unsigned*)Tb, rc, col, perm, dis, b4,
                                          nullptr, nullptr, hout);

    k_poolhead<<<N_GRAPHS, 256, 0, stream>>>(hout, batch, Wr1, br1, Wr2, br2, Wr3, br3, out);
}

// Round 19
// 232.572 us; speedup vs baseline: 1.0375x; 1.0375x over previous
//
#include <hip/hip_runtime.h>
#include <hip/hip_bf16.h>

typedef __hip_bfloat16 bf16;
typedef short bf16x8 __attribute__((ext_vector_type(8)));
typedef float f32x4 __attribute__((ext_vector_type(4)));
typedef float f32x2 __attribute__((ext_vector_type(2)));

#define N_NODES 100000
#define N_EDGES 3200000
#define N_GRAPHS 512
#define NBKT    ((N_NODES + 255) / 256)               // 391 buckets of 256 nodes
#define CAP     10496                                 // slots per bucket window (8-aligned)
#define EPB     16384                                 // edges per k_bucket block
#define NBLK_A  ((N_EDGES + EPB - 1) / EPB)           // 196
#define FP4_SCALE 16.0f
#define FP4_INV   (1.0f / 16.0f)

// ---------- fp4 e2m1 decode: dword of 8 nibbles -> ae[2] (even feats), ao[2] (odd) ----------
// mag LUT (fp8 e4m3 bytes): 0,0.5,1,1.5,2,3,4,6 -> 00,30,38,3C,40,44,48,4C

__device__ inline void accf4(f32x2* ae, f32x2* ao, unsigned d) {
#if __has_builtin(__builtin_amdgcn_cvt_pk_f32_fp8) && __has_builtin(__builtin_amdgcn_perm)
    unsigned lo8 = __builtin_amdgcn_perm(0x4C484440u, 0x3C383000u, d & 0x07070707u)
                 | ((d & 0x08080808u) << 4);
    unsigned hi8 = __builtin_amdgcn_perm(0x4C484440u, 0x3C383000u, (d >> 4) & 0x07070707u)
                 | (d & 0x80808080u);
    ae[0] += __builtin_amdgcn_cvt_pk_f32_fp8((int)lo8, false);
    ae[1] += __builtin_amdgcn_cvt_pk_f32_fp8((int)lo8, true);
    ao[0] += __builtin_amdgcn_cvt_pk_f32_fp8((int)hi8, false);
    ao[1] += __builtin_amdgcn_cvt_pk_f32_fp8((int)hi8, true);
#else
    #pragma unroll
    for (int i = 0; i < 4; ++i) {
        unsigned by = (d >> (8 * i)) & 0xFFu;
        unsigned ln = by & 7u, hn = (by >> 4) & 7u;
        float lv = (ln < 2) ? (float)ln * 0.5f : 0.5f * (float)(1 << ((ln >> 1) - 1)) * (2 + (ln & 1));
        float hv = (hn < 2) ? (float)hn * 0.5f : 0.5f * (float)(1 << ((hn >> 1) - 1)) * (2 + (hn & 1));
        if (by & 8u) lv = -lv;
        if (by & 0x80u) hv = -hv;
        ae[i >> 1][i & 1] += lv;
        ao[i >> 1][i & 1] += hv;
    }
#endif
}

// ---------- fp4 encode: f32 -> nibble (RNE over the e2m1 grid) ----------

__device__ inline unsigned fp4n(float v) {
    unsigned s = (__float_as_uint(v) >> 28) & 8u;
    float x = fabsf(v);
    unsigned n = (unsigned)(x >= 0.25f) + (x >= 0.75f) + (x >= 1.25f) + (x >= 1.75f)
               + (x >= 2.5f) + (x >= 3.5f) + (x >= 5.0f);
    return s | n;
}

__device__ inline unsigned short f2bf(float x) {
    unsigned u = __float_as_uint(x);
    return (unsigned short)((u + 0x7FFF + ((u >> 16) & 1)) >> 16);
}

// ---------- setup: Wc/bc, Wfrag, gcur, dummy rows — one kernel ----------

__global__ void k_setup(const float* __restrict__ W_emb, const float* __restrict__ b_emb,
                        const float* __restrict__ W1, const float* __restrict__ W2,
                        const float* __restrict__ W3, const float* __restrict__ W4,
                        float* __restrict__ Wc, float* __restrict__ bc,
                        unsigned short* __restrict__ Wfrag, int* __restrict__ gcur,
                        unsigned* __restrict__ ta, unsigned* __restrict__ tb) {
    int blk = blockIdx.x, t = threadIdx.x;
    if (blk == 0) {
        for (int i = t; i < 32 * 64; i += 256) {
            int a = i / 64, b = i % 64;
            float acc = 0.f;
            for (int k = 0; k < 64; ++k) acc += W_emb[a * 64 + k] * W1[k * 64 + b];
            Wc[i] = acc;
        }
        if (t < 64) {
            float acc = 0.f;
            for (int k = 0; k < 64; ++k) acc += b_emb[k] * W1[k * 64 + t];
            bc[t] = acc;
        }
    } else if (blk <= 3) {
        const float* W = (blk == 1) ? W2 : (blk == 2) ? W3 : W4;
        unsigned short* dst = Wfrag + (size_t)(blk - 1) * 4096;
        for (int i = 0; i < 16; ++i) {
            int flat = t * 16 + i;
            int j = flat & 7, lane = (flat >> 3) & 63, mt = (flat >> 9) & 3, kt = flat >> 11;
            int m = mt * 16 + (lane & 15);
            int k = kt * 32 + ((lane >> 4) << 3) + j;
            dst[flat] = f2bf(W[k * 64 + m]);
        }
    } else {
        for (int b = t; b < NBKT; b += 256) gcur[b] = b * CAP;
        if (t < 8) {
            size_t o = (size_t)N_NODES * 8 + t;
            ta[o] = 0; tb[o] = 0;
        }
    }
}

// ---------- Pass A: bin edges by dst>>8, per-wave LDS histograms ----------

__global__ void __launch_bounds__(512) k_bucket(const int* __restrict__ ei,
                                                int* __restrict__ gcur,
                                                int* __restrict__ ebuf) {
    __shared__ int cnt[8][NBKT];
    __shared__ int base[8][NBKT];
    int t = threadIdx.x, w = t >> 6;
    for (int i = t; i < 8 * NBKT; i += 512) ((int*)cnt)[i] = 0;
    __syncthreads();
    int e0 = blockIdx.x * EPB + t;
    int sv[32], dv[32];
    #pragma unroll
    for (int j = 0; j < 32; ++j) {
        int e = e0 + j * 512;
        if (e < N_EDGES) {
            sv[j] = ei[e];
            dv[j] = ei[N_EDGES + e];
            atomicAdd(&cnt[w][dv[j] >> 8], 1);
        } else dv[j] = -1;
    }
    __syncthreads();
    for (int b = t; b < NBKT; b += 512) {
        int tot = 0, c[8];
        #pragma unroll
        for (int ww = 0; ww < 8; ++ww) { c[ww] = cnt[ww][b]; tot += c[ww]; }
        int g = tot ? atomicAdd(&gcur[b], tot) : 0;
        #pragma unroll
        for (int ww = 0; ww < 8; ++ww) { base[ww][b] = g; g += c[ww]; cnt[ww][b] = 0; }
    }
    __syncthreads();
    #pragma unroll
    for (int j = 0; j < 32; ++j) {
        if (dv[j] >= 0) {
            int b = dv[j] >> 8;
            int r = atomicAdd(&cnt[w][b], 1);
            ebuf[base[w][b] + r] = (sv[j] << 8) | (dv[j] & 255);
        }
    }
}

// ---------- Pass B: per-bucket histogram -> rc/dis, 8-aligned col, pad-gap dummies ----------

__global__ void __launch_bounds__(256) k_fill2(const int* __restrict__ ebuf,
                                               const int* __restrict__ gcur,
                                               int2* __restrict__ rc,
                                               float* __restrict__ dis,
                                               int* __restrict__ col) {
    __shared__ int cnt[256];
    __shared__ int sc[256];
    __shared__ int exs[256];
    __shared__ int cur[256];
    int b = blockIdx.x, t = threadIdx.x;
    int n0 = b * 256;
    int nrec = gcur[b] - b * CAP;
    const int* eb = ebuf + (size_t)b * CAP;
    int* cw = col + (size_t)b * CAP;
    cnt[t] = 0; cur[t] = 0;
    __syncthreads();
    for (int i = t; i < nrec; i += 256)
        atomicAdd(&cnt[eb[i] & 255], 1);
    __syncthreads();
    int c0 = cnt[t];
    int a8 = (c0 + 7) & ~7;
    sc[t] = a8; __syncthreads();
    for (int off = 1; off < 256; off <<= 1) {
        int u = (t >= off) ? sc[t - off] : 0;
        __syncthreads();
        sc[t] += u;
        __syncthreads();
    }
    int myex = sc[t] - a8;
    exs[t] = myex;
    int n = n0 + t;
    if (n < N_NODES) {
        rc[n] = make_int2(b * CAP + myex, c0);
        dis[n] = rsqrtf((float)(c0 + 1));
    }
    for (int i = myex + c0; i < myex + a8; ++i) cw[i] = N_NODES;
    __syncthreads();
    for (int i = t; i < nrec; i += 256) {
        int rec = eb[i];
        int dl = rec & 255;
        cw[exs[dl] + atomicAdd(&cur[dl], 1)] = rec >> 8;
    }
}

// ---------- layer-1 matmul -> fp4 table (nibble-packed, 32B rows) ----------

__global__ void __launch_bounds__(256) k_mm1(const float* __restrict__ inp,
                                             const float* __restrict__ W,
                                             const float* __restrict__ bias,
                                             const float* __restrict__ dis,
                                             unsigned char* __restrict__ T) {
    __shared__ float Wl[32][64];
    __shared__ float hs[16][32];
    int t = threadIdx.x;
    for (int i = t; i < 32 * 64; i += 256) Wl[i / 64][i % 64] = W[i];
    int row0 = blockIdx.x * 16;
    for (int i = t; i < 16 * 32; i += 256) {
        int r = row0 + i / 32, k = i % 32;
        hs[i / 32][k] = inp[(size_t)r * 32 + k];
    }
    __syncthreads();
    int c = t & 63, rg = t >> 6;
    float a0 = 0, a1 = 0, a2 = 0, a3 = 0;
    #pragma unroll 4
    for (int k = 0; k < 32; ++k) {
        float wv = Wl[k][c];
        a0 += hs[rg * 4 + 0][k] * wv;
        a1 += hs[rg * 4 + 1][k] * wv;
        a2 += hs[rg * 4 + 2][k] * wv;
        a3 += hs[rg * 4 + 3][k] * wv;
    }
    float bv = bias[c];
    int r = row0 + rg * 4;
    unsigned n0 = fp4n(FP4_SCALE * dis[r + 0] * (a0 + bv));
    unsigned n1 = fp4n(FP4_SCALE * dis[r + 1] * (a1 + bv));
    unsigned n2 = fp4n(FP4_SCALE * dis[r + 2] * (a2 + bv));
    unsigned n3 = fp4n(FP4_SCALE * dis[r + 3] * (a3 + bv));
    unsigned p0 = __shfl_xor(n0, 1), p1 = __shfl_xor(n1, 1);
    unsigned p2 = __shfl_xor(n2, 1), p3 = __shfl_xor(n3, 1);
    if ((c & 1) == 0) {
        size_t boff = (size_t)(c >> 1);
        T[(size_t)(r + 0) * 32 + boff] = (unsigned char)(n0 | (p0 << 4));
        T[(size_t)(r + 1) * 32 + boff] = (unsigned char)(n1 | (p1 << 4));
        T[(size_t)(r + 2) * 32 + boff] = (unsigned char)(n2 | (p2 << 4));
        T[(size_t)(r + 3) * 32 + boff] = (unsigned char)(n3 | (p3 << 4));
    }
}

// ---------- FUSED AGG + COMBINE (fp4): 32 rows/block, 4 waves ----------
// agg phase: 8 rows/wave x 8 feature-dwords, 8-deep pipelined gathers;
// then h = relu(dis/S*agg + b) -> LDS -> MFMA h@Wn -> next fp4 table.
// LAST: write relu'd h (bf16) to hout instead.

template<bool LAST>
__global__ void __launch_bounds__(256, 8) k_aggc(const unsigned* __restrict__ tph,
                                                 const int2* __restrict__ rc,
                                                 const int* __restrict__ col,
                                                 const float* __restrict__ dis,
                                                 const float* __restrict__ bias,
                                                 const unsigned short* __restrict__ Wfrag,
                                                 unsigned char* __restrict__ Tn,
                                                 unsigned short* __restrict__ hout) {
    __shared__ unsigned short h_lds[32][72];
    int t = threadIdx.x;
    int rowbase = blockIdx.x * 32;
    int row = rowbase + (t >> 3);
    int sl = t & 7;
    f32x2 ae[2] = {{0.f, 0.f}, {0.f, 0.f}};
    f32x2 ao[2] = {{0.f, 0.f}, {0.f, 0.f}};
    accf4(ae, ao, tph[(size_t)row * 8 + sl]);          // self-loop term
    int2 r = rc[row];
    int nit = (r.y + 7) >> 3;                          // 8-edge iterations
    const int* cp = col + r.x;
    if (nit > 0) {
        int4 c0 = *(const int4*)(cp + 0);
        int4 c1 = *(const int4*)(cp + 4);
        for (int it = 1; it < nit; ++it) {
            unsigned v0 = tph[(size_t)c0.x * 8 + sl];
            unsigned v1 = tph[(size_t)c0.y * 8 + sl];
            unsigned v2 = tph[(size_t)c0.z * 8 + sl];
            unsigned v3 = tph[(size_t)c0.w * 8 + sl];
            unsigned v4 = tph[(size_t)c1.x * 8 + sl];
            unsigned v5 = tph[(size_t)c1.y * 8 + sl];
            unsigned v6 = tph[(size_t)c1.z * 8 + sl];
            unsigned v7 = tph[(size_t)c1.w * 8 + sl];
            const int* np = cp + it * 8;               // prefetch next 8 cols
            c0 = *(const int4*)(np + 0);
            c1 = *(const int4*)(np + 4);
            accf4(ae, ao, v0); accf4(ae, ao, v1); accf4(ae, ao, v2); accf4(ae, ao, v3);
            accf4(ae, ao, v4); accf4(ae, ao, v5); accf4(ae, ao, v6); accf4(ae, ao, v7);
        }
        unsigned v0 = tph[(size_t)c0.x * 8 + sl];
        unsigned v1 = tph[(size_t)c0.y * 8 + sl];
        unsigned v2 = tph[(size_t)c0.z * 8 + sl];
        unsigned v3 = tph[(size_t)c0.w * 8 + sl];
        unsigned v4 = tph[(size_t)c1.x * 8 + sl];
        unsigned v5 = tph[(size_t)c1.y * 8 + sl];
        unsigned v6 = tph[(size_t)c1.z * 8 + sl];
        unsigned v7 = tph[(size_t)c1.w * 8 + sl];
        accf4(ae, ao, v0); accf4(ae, ao, v1); accf4(ae, ao, v2); accf4(ae, ao, v3);
        accf4(ae, ao, v4); accf4(ae, ao, v5); accf4(ae, ao, v6); accf4(ae, ao, v7);
    }
    // h = relu(dis/S * agg + bias), features sl*8 .. sl*8+7 (even in ae, odd in ao)
    float ds = dis[row] * FP4_INV;
    int f0 = sl * 8;
    float h0 = fmaxf(ds * ae[0].x + bias[f0 + 0], 0.f);
    float h1 = fmaxf(ds * ao[0].x + bias[f0 + 1], 0.f);
    float h2 = fmaxf(ds * ae[0].y + bias[f0 + 2], 0.f);
    float h3 = fmaxf(ds * ao[0].y + bias[f0 + 3], 0.f);
    float h4 = fmaxf(ds * ae[1].x + bias[f0 + 4], 0.f);
    float h5 = fmaxf(ds * ao[1].x + bias[f0 + 5], 0.f);
    float h6 = fmaxf(ds * ae[1].y + bias[f0 + 6], 0.f);
    float h7 = fmaxf(ds * ao[1].y + bias[f0 + 7], 0.f);
    uint4 o;
    o.x = (unsigned)f2bf(h0) | ((unsigned)f2bf(h1) << 16);
    o.y = (unsigned)f2bf(h2) | ((unsigned)f2bf(h3) << 16);
    o.z = (unsigned)f2bf(h4) | ((unsigned)f2bf(h5) << 16);
    o.w = (unsigned)f2bf(h6) | ((unsigned)f2bf(h7) << 16);
    if (LAST) {
        *(uint4*)(hout + (size_t)row * 64 + f0) = o;
        return;
    }
    *(uint4*)&h_lds[row - rowbase][f0] = o;
    __syncthreads();
    // MFMA: wave w handles row-group (w&1), mt-tiles {2*(w>>1), 2*(w>>1)+1}
    int w = t >> 6, l = t & 63;
    int rg = w & 1, mt0 = (w >> 1) << 1;
    f32x4 acc[2] = {{0, 0, 0, 0}, {0, 0, 0, 0}};
    const bf16x8* wf = (const bf16x8*)Wfrag;
    #pragma unroll
    for (int kt = 0; kt < 2; ++kt) {
        bf16x8 bfr = *(const bf16x8*)&h_lds[rg * 16 + (l & 15)][kt * 32 + ((l >> 4) << 3)];
        #pragma unroll
        for (int mi = 0; mi < 2; ++mi) {
            bf16x8 afr = wf[(kt * 4 + mt0 + mi) * 64 + l];
            acc[mi] = __builtin_amdgcn_mfma_f32_16x16x32_bf16(afr, bfr, acc[mi], 0, 0, 0);
        }
    }
    int hrow = rowbase + rg * 16 + (l & 15);
    float sc2 = FP4_SCALE * dis[hrow];
    #pragma unroll
    for (int mi = 0; mi < 2; ++mi) {
        int colbase = (mt0 + mi) * 16 + ((l >> 4) << 2);
        unsigned short v = (unsigned short)(fp4n(sc2 * acc[mi][0])
                           | (fp4n(sc2 * acc[mi][1]) << 4)
                           | (fp4n(sc2 * acc[mi][2]) << 8)
                           | (fp4n(sc2 * acc[mi][3]) << 12));
        *(unsigned short*)(Tn + (size_t)hrow * 32 + (colbase >> 1)) = v;
    }
}

// ---------- pool (h pre-activated) + MLP head + log_softmax ----------

__global__ void __launch_bounds__(256) k_poolhead(const unsigned short* __restrict__ h,
                                                  const int* __restrict__ batch,
                                                  const float* __restrict__ Wr1, const float* __restrict__ br1,
                                                  const float* __restrict__ Wr2, const float* __restrict__ br2,
                                                  const float* __restrict__ Wr3, const float* __restrict__ br3,
                                                  float* __restrict__ out) {
    __shared__ float part[4][64];
    __shared__ float p[64], r1[32], r2[16], lg[10];
    __shared__ int seg[2];
    int g = blockIdx.x, t = threadIdx.x;
    if (t < 2) {
        int key = g + t;
        int lo = 0, hi = N_NODES;
        while (lo < hi) { int m = (lo + hi) >> 1; if (batch[m] < key) lo = m + 1; else hi = m; }
        seg[t] = lo;
    }
    __syncthreads();
    int start = seg[0], end = seg[1];
    int w = t >> 6, grp = (t >> 4) & 3, sl = t & 15;
    float a[4] = {0.f, 0.f, 0.f, 0.f};
    for (int r = start + w * 4 + grp; r < end; r += 16) {
        ushort4 v = *(const ushort4*)(h + (size_t)r * 64 + sl * 4);
        a[0] += __uint_as_float((unsigned)v.x << 16);
        a[1] += __uint_as_float((unsigned)v.y << 16);
        a[2] += __uint_as_float((unsigned)v.z << 16);
        a[3] += __uint_as_float((unsigned)v.w << 16);
    }
    #pragma unroll
    for (int j = 0; j < 4; ++j) {
        a[j] += __shfl_xor(a[j], 16);
        a[j] += __shfl_xor(a[j], 32);
    }
    if (sl == (t & 63)) {
        #pragma unroll
        for (int j = 0; j < 4; ++j) part[w][sl * 4 + j] = a[j];
    }
    __syncthreads();
    if (t < 64) {
        float s = part[0][t] + part[1][t] + part[2][t] + part[3][t];
        float c = fmaxf((float)(end - start), 1.f);
        p[t] = s / c;
    }
    __syncthreads();
    if (t < 32) {
        float acc = br1[t];
        for (int k = 0; k < 64; ++k) acc += p[k] * Wr1[k * 32 + t];
        r1[t] = fmaxf(acc, 0.f);
    }
    __syncthreads();
    if (t < 16) {
        float acc = br2[t];
        for (int k = 0; k < 32; ++k) acc += r1[k] * Wr2[k * 16 + t];
        r2[t] = fmaxf(acc, 0.f);
    }
    __syncthreads();
    if (t < 10) {
        float acc = br3[t];
        for (int k = 0; k < 16; ++k) acc += r2[k] * Wr3[k * 10 + t];
        lg[t] = acc;
    }
    __syncthreads();
    if (t < 10) {
        float m = -1e30f;
        for (int j = 0; j < 10; ++j) m = fmaxf(m, lg[j]);
        float s = 0.f;
        for (int j = 0; j < 10; ++j) s += expf(lg[j] - m);
        out[g * 10 + t] = lg[t] - m - logf(s);
    }
}

extern "C" void kernel_launch(void* const* d_in, const int* in_sizes, int n_in,
                              void* d_out, int out_size, void* d_ws, size_t ws_size,
                              hipStream_t stream) {
    const float* x     = (const float*)d_in[0];
    const int*   ei    = (const int*)d_in[1];
    const int*   batch = (const int*)d_in[2];
    const float* W_emb = (const float*)d_in[4];
    const float* b_emb = (const float*)d_in[5];
    const float* W1    = (const float*)d_in[6];
    const float* b1    = (const float*)d_in[7];
    const float* W2    = (const float*)d_in[8];
    const float* b2    = (const float*)d_in[9];
    const float* W3    = (const float*)d_in[10];
    const float* b3    = (const float*)d_in[11];
    const float* W4    = (const float*)d_in[12];
    const float* b4    = (const float*)d_in[13];
    const float* Wr1   = (const float*)d_in[14];
    const float* br1   = (const float*)d_in[15];
    const float* Wr2   = (const float*)d_in[16];
    const float* br2   = (const float*)d_in[17];
    const float* Wr3   = (const float*)d_in[18];
    const float* br3   = (const float*)d_in[19];
    float* out = (float*)d_out;

    char* ws = (char*)d_ws;
    size_t off = 0;
    auto alloc = [&](size_t b) { char* p = ws + off; off += (b + 511) & ~(size_t)511; return p; };
    size_t TBYTES = (size_t)(N_NODES + 1) * 32;
    int*   col    = (int*)  alloc((size_t)NBKT * CAP * 4);     // 16.4 MB
    int*   ebuf   = (int*)  alloc((size_t)NBKT * CAP * 4);     // later reused as hout
    unsigned char* Ta = (unsigned char*)alloc(TBYTES);         // fp4 tables (+dummy row)
    unsigned char* Tb = (unsigned char*)alloc(TBYTES);
    int2*  rc     = (int2*) alloc((size_t)N_NODES * 8);
    float* dis    = (float*)alloc((size_t)N_NODES * 4);
    int*   gcur   = (int*)  alloc((size_t)NBKT * 4);
    float* Wc     = (float*)alloc(32 * 64 * 4);
    float* bc     = (float*)alloc(64 * 4);
    unsigned short* Wfrag = (unsigned short*)alloc(3 * 4096 * 2);

    unsigned short* hout = (unsigned short*)ebuf;    // alias: h lives where ebuf was

    k_setup<<<5, 256, 0, stream>>>(W_emb, b_emb, W1, W2, W3, W4, Wc, bc, Wfrag, gcur,
                                   (unsigned*)Ta, (unsigned*)Tb);
    k_bucket<<<NBLK_A, 512, 0, stream>>>(ei, gcur, ebuf);
    k_fill2<<<NBKT, 256, 0, stream>>>(ebuf, gcur, rc, dis, col);

    int nbm = N_NODES / 16;        // 6250
    int nba = N_NODES / 32;        // 3125

    k_mm1<<<nbm, 256, 0, stream>>>(x, Wc, bc, dis, Ta);

    // layers 1-3: fused agg+combine, ping-pong fp4 tables
    k_aggc<false><<<nba, 256, 0, stream>>>((const unsigned*)Ta, rc, col, dis, b1,
                                           Wfrag + 0 * 4096, Tb, nullptr);
    k_aggc<false><<<nba, 256, 0, stream>>>((const unsigned*)Tb, rc, col, dis, b2,
                                           Wfrag + 1 * 4096, Ta, nullptr);
    k_aggc<false><<<nba, 256, 0, stream>>>((const unsigned*)Ta, rc, col, dis, b3,
                                           Wfrag + 2 * 4096, Tb, nullptr);
    // layer 4: fused agg + bias/relu -> h
    k_aggc<true><<<nba, 256, 0, stream>>>((const unsigned*)Tb, rc, col, dis, b4,
                                          nullptr, nullptr, hout);

    k_poolhead<<<N_GRAPHS, 256, 0, stream>>>(hout, batch, Wr1, br1, Wr2, br2, Wr3, br3, out);
}